// Round 6
// baseline (3328.927 us; speedup 1.0000x reference)
//
#include <hip/hip_runtime.h>

#define DI __device__ __forceinline__

constexpr int BB   = 128;   // batch
constexpr int TT   = 512;   // seq len
constexpr int TT1  = TT + 1;
constexpr int HH   = 768;   // hidden
constexpr int G3   = 3 * HH;   // 2304
constexpr int VOC  = 128;

// partitioning: 8 row-groups (16 rows) x 48 unit-waves (16 units), 1 wave per block
constexpr int NG   = 8;     // sync groups (16 batch rows each)
constexpr int NW   = 48;    // waves per group (16 units each)
constexpr int KC   = 24;    // k-chunks of 32 (768 = 24*32)

// workspace offsets (bytes); total ~5.52 MB
constexpr size_t OFF_GE   = 0;                      // [VOC][G3] f32  = 1,179,648
constexpr size_t OFF_WIMG = 1179648;                // [NW][3][KC][64][8] f16 = 3,538,944
constexpr size_t OFF_H16  = OFF_WIMG + 3538944;     // [2][BB][HH] f16 = 393,216
constexpr size_t OFF_H32  = OFF_H16 + 393216;       // [BB][HH] f32   = 393,216
constexpr size_t OFF_CNT  = OFF_H32 + 393216;       // [NG][TT1] int  = 16,416

constexpr int LDS_W_BYTES = 3 * KC * 64 * 16;       // 73,728 (W fragments)
constexpr int LDS_BYTES   = LDS_W_BYTES + 1024;     // 74,752 -> 2 blocks/CU

typedef _Float16 f16x8 __attribute__((ext_vector_type(8)));
typedef float    f32x4 __attribute__((ext_vector_type(4)));

DI float sigm(float x) { return __builtin_amdgcn_rcpf(1.0f + __expf(-x)); }
DI float tanh_fast(float x) {
  float e = __expf(-2.0f * fabsf(x));
  float r = (1.0f - e) * __builtin_amdgcn_rcpf(1.0f + e);
  return copysignf(r, x);
}

// device-coherent (L2-bypassing, coherent at MALL/L3) memory ops
DI f16x8 load_dc_x4(const void* p) {
  f16x8 r;
  asm volatile("global_load_dwordx4 %0, %1, off sc0 sc1"
               : "=v"(r) : "v"(p) : "memory");
  return r;
}
DI void store_dc_x2(void* p, uint2 v) {
  asm volatile("global_store_dwordx2 %0, %1, off sc0 sc1"
               :: "v"(p), "v"(v) : "memory");
}
DI int load_cnt(const int* p) {
  int r;
  asm volatile("global_load_dword %0, %1, off sc0 sc1\n\ts_waitcnt vmcnt(0)"
               : "=v"(r) : "v"(p) : "memory");
  return r;
}
DI void wait_vm0() { asm volatile("s_waitcnt vmcnt(0)" ::: "memory"); }
DI void wait_lgkm0() { asm volatile("s_waitcnt lgkmcnt(0)" ::: "memory"); }

// ---------------- K0: zero step counters ----------------
__global__ void k_zero(int* cnt, int n) {
  int i = blockIdx.x * 256 + threadIdx.x;
  if (i < n) cnt[i] = 0;
}

// ---------------- K1: W_hh -> fp16 MFMA B-fragment image ----------------
// layout [tile 48][gate 3][kc 24][lane 64] f16x8
// B[k][n]: n = tile*16 + (lane&15), k = kc*32 + (lane>>4)*8 + q
// value = W_hh[gate*768 + n][k]
__global__ void k_prep_w(const float* __restrict__ Whh, _Float16* __restrict__ wimg) {
  int tid = blockIdx.x * 256 + threadIdx.x;       // 48*3*24*64 = 221,184 total
  if (tid >= NW * 3 * KC * 64) return;
  int l  = tid & 63;
  int fi = tid >> 6;
  int kc = fi % KC;
  int nt = (fi / KC) % 3;
  int j  = fi / (KC * 3);
  int g  = nt * HH + j * 16 + (l & 15);
  int k0 = kc * 32 + (l >> 4) * 8;
  const float* src = Whh + (size_t)g * HH + k0;
  f16x8 o;
#pragma unroll
  for (int q = 0; q < 8; ++q) o[q] = (_Float16)src[q];
  ((f16x8*)wimg)[tid] = o;
}

// ---------------- K2: ge[v][g] = emb[v,:] . W_ih[g,:] + b_ih[g] ----------------
__global__ void k_prep_ge(const float* __restrict__ emb, const float* __restrict__ Wih,
                          const float* __restrict__ bih, float* __restrict__ ge) {
  int g  = blockIdx.x * 256 + threadIdx.x;
  int v0 = blockIdx.y * 16;
  float acc[16];
  float b = bih[g];
#pragma unroll
  for (int i = 0; i < 16; ++i) acc[i] = b;
  const float* wrow = Wih + (size_t)g * HH;
  for (int e = 0; e < HH; e += 4) {
    float4 w = *(const float4*)(wrow + e);
#pragma unroll
    for (int i = 0; i < 16; ++i) {
      float4 m = *(const float4*)(emb + (size_t)(v0 + i) * HH + e);
      acc[i] = fmaf(w.x, m.x, acc[i]);
      acc[i] = fmaf(w.y, m.y, acc[i]);
      acc[i] = fmaf(w.z, m.z, acc[i]);
      acc[i] = fmaf(w.w, m.w, acc[i]);
    }
  }
#pragma unroll
  for (int i = 0; i < 16; ++i) ge[(size_t)(v0 + i) * G3 + g] = acc[i];
}

// ---------------- K3: persistent GRU recurrence ----------------
// 384 blocks x 64 thr (1 wave). block -> (grp = bid/NW, j = bid%NW):
// rows [16*grp,+16) x units [16*j,+16). Counter cnt[grp][t] == 48 <=> h(t) published.
__global__ __launch_bounds__(64, 1) void k_gru(
    const int* __restrict__ x,       // [BB][TT]
    const float* __restrict__ ge,    // [VOC][G3]
    const float* __restrict__ bhh,   // [G3]
    const _Float16* __restrict__ wimg,
    _Float16* h16,                   // [2][BB][HH]
    float* __restrict__ h32,         // [BB][HH]
    int* cnt)                        // [NG][TT1]
{
  extern __shared__ char smem[];
  _Float16* st = (_Float16*)(smem + LDS_W_BYTES);   // [16][20] halfs

  const int lane = threadIdx.x;
  const int bid  = blockIdx.x;
  const int grp  = bid / NW;
  const int j    = bid % NW;
  const int bm   = grp * 16;        // this wave's 16 batch rows
  const int u0   = j * 16;          // this wave's 16 hidden units
  int* gcnt = cnt + grp * TT1;

  // stage this tile's W fragments into LDS (73,728 B = 4608 uint4 / 64 = 72)
  {
    const uint4* src = (const uint4*)(wimg + (size_t)j * (3 * KC * 64 * 8));
    uint4* dst = (uint4*)smem;
#pragma unroll 8
    for (int r = 0; r < 72; ++r) dst[lane + 64 * r] = src[lane + 64 * r];
  }

  const int c16 = lane & 15;   // D col / A row within tile
  const int kr  = lane >> 4;   // k sub-chunk selector

  const float bh_r = bhh[0 * HH + u0 + c16];
  const float bh_z = bhh[1 * HH + u0 + c16];
  const float bh_n = bhh[2 * HH + u0 + c16];

  float hprev[4] = {0.f, 0.f, 0.f, 0.f};

  _Float16* hb0 = h16;
  _Float16* hb1 = h16 + (size_t)BB * HH;
  const f16x8* bfr = (const f16x8*)smem;

  // prologue gathers for t=0
  float ger[4], gez[4], gen[4];
#pragma unroll
  for (int q = 0; q < 4; ++q) {
    int xv = x[(size_t)(bm + kr * 4 + q) * TT + 0];
    const float* gp = ge + (size_t)xv * G3 + u0 + c16;
    ger[q] = gp[0 * HH];
    gez[q] = gp[1 * HH];
    gen[q] = gp[2 * HH];
  }

  int budget = 1 << 20;   // global poll budget: bug => wrong result, not timeout

  for (int t = 0; t < TT; ++t) {
    f32x4 acc0 = {bh_r, bh_r, bh_r, bh_r};
    f32x4 acc1 = {bh_z, bh_z, bh_z, bh_z};
    f32x4 acc2 = {bh_n, bh_n, bh_n, bh_n};

    if (t > 0) {
      // ---- poll single aggregated counter for this group/step ----
      const int* cp = gcnt + t;
      for (;;) {
        int c = load_cnt(cp);
        if (c >= NW) break;
        if (--budget < 0) break;
        __builtin_amdgcn_s_sleep(1);
      }
      asm volatile("" ::: "memory");  // keep A-loads below the poll

      // ---- A fragments: 24 x 16B device-coherent loads ----
      const _Float16* hb = (t & 1) ? hb1 : hb0;
      const char* ab = (const char*)(hb + (size_t)(bm + c16) * HH) + kr * 16;
      f16x8 a[KC];
#pragma unroll
      for (int kc = 0; kc < KC; ++kc) a[kc] = load_dc_x4(ab + kc * 64);
      wait_vm0();
      __builtin_amdgcn_sched_barrier(0);  // MFMAs must not hoist above the wait

      // ---- gh = h . W^T : 3 gates x 24 k-chunks, B from LDS ----
#pragma unroll
      for (int kc = 0; kc < KC; ++kc) {
        acc0 = __builtin_amdgcn_mfma_f32_16x16x32_f16(a[kc], bfr[(0 * KC + kc) * 64 + lane], acc0, 0, 0, 0);
        acc1 = __builtin_amdgcn_mfma_f32_16x16x32_f16(a[kc], bfr[(1 * KC + kc) * 64 + lane], acc1, 0, 0, 0);
        acc2 = __builtin_amdgcn_mfma_f32_16x16x32_f16(a[kc], bfr[(2 * KC + kc) * 64 + lane], acc2, 0, 0, 0);
      }
    }

    // ---- gates + state update (fp32) ----
    float hv[4];
#pragma unroll
    for (int q = 0; q < 4; ++q) {
      float r = sigm(acc0[q] + ger[q]);
      float z = sigm(acc1[q] + gez[q]);
      float n = tanh_fast(gen[q] + r * acc2[q]);
      float h = n + z * (hprev[q] - n);
      hprev[q] = h;
      hv[q] = h;
    }

    if (t == TT - 1) {
#pragma unroll
      for (int q = 0; q < 4; ++q)
        h32[(size_t)(bm + kr * 4 + q) * HH + u0 + c16] = hv[q];
    } else {
      // ---- pack 16x16 f16 tile via LDS (stride 20) ----
#pragma unroll
      for (int q = 0; q < 4; ++q)
        st[(kr * 4 + q) * 20 + c16] = (_Float16)hv[q];
      wait_lgkm0();
      __builtin_amdgcn_sched_barrier(0);
      int rr = lane >> 2;       // row within tile
      int qq = lane & 3;        // 4-unit quarter
      uint2 v = *(const uint2*)&st[rr * 20 + qq * 4];
      _Float16* hn = (t & 1) ? hb0 : hb1;   // buf[(t+1)&1]
      store_dc_x2((char*)(hn + (size_t)(bm + rr) * HH + u0 + qq * 4), v);

      // ---- overlap t+1 gathers (cached) with the store flight ----
#pragma unroll
      for (int q = 0; q < 4; ++q) {
        int xv = x[(size_t)(bm + kr * 4 + q) * TT + (t + 1)];
        const float* gp = ge + (size_t)xv * G3 + u0 + c16;
        ger[q] = gp[0 * HH];
        gez[q] = gp[1 * HH];
        gen[q] = gp[2 * HH];
      }

      wait_vm0();               // h stores globally visible before counting
      if (lane == 0)
        __hip_atomic_fetch_add(gcnt + t + 1, 1, __ATOMIC_RELAXED,
                               __HIP_MEMORY_SCOPE_AGENT);
    }
  }
}

// ---------------- K4: out = h32 @ fc_W^T + fc_b ----------------
__global__ void k_fc(const float* __restrict__ h32, const float* __restrict__ fcW,
                     const float* __restrict__ fcb, float* __restrict__ out) {
  int o  = blockIdx.x * 256 + threadIdx.x;   // 768
  int b0 = blockIdx.y * 16;                  // 128
  float acc[16];
  float bi = fcb[o];
#pragma unroll
  for (int i = 0; i < 16; ++i) acc[i] = bi;
  const float* wrow = fcW + (size_t)o * HH;
  for (int e = 0; e < HH; e += 4) {
    float4 w = *(const float4*)(wrow + e);
#pragma unroll
    for (int i = 0; i < 16; ++i) {
      float4 m = *(const float4*)(h32 + (size_t)(b0 + i) * HH + e);
      acc[i] = fmaf(w.x, m.x, acc[i]);
      acc[i] = fmaf(w.y, m.y, acc[i]);
      acc[i] = fmaf(w.z, m.z, acc[i]);
      acc[i] = fmaf(w.w, m.w, acc[i]);
    }
  }
#pragma unroll
  for (int i = 0; i < 16; ++i) out[(size_t)(b0 + i) * HH + o] = acc[i];
}

extern "C" void kernel_launch(void* const* d_in, const int* in_sizes, int n_in,
                              void* d_out, int out_size, void* d_ws, size_t ws_size,
                              hipStream_t stream) {
  const int*   x   = (const int*)d_in[0];
  const float* emb = (const float*)d_in[1];
  const float* Wih = (const float*)d_in[2];
  const float* Whh = (const float*)d_in[3];
  const float* bih = (const float*)d_in[4];
  const float* bhh = (const float*)d_in[5];
  const float* fcW = (const float*)d_in[6];
  const float* fcb = (const float*)d_in[7];
  float* out = (float*)d_out;

  char* ws = (char*)d_ws;
  float*     ge   = (float*)(ws + OFF_GE);
  _Float16*  wimg = (_Float16*)(ws + OFF_WIMG);
  _Float16*  h16  = (_Float16*)(ws + OFF_H16);
  float*     h32  = (float*)(ws + OFF_H32);
  int*       cnt  = (int*)(ws + OFF_CNT);

  // zero step counters (8 * 513 = 4104 ints)
  k_zero<<<17, 256, 0, stream>>>(cnt, NG * TT1);
  k_prep_w<<<864, 256, 0, stream>>>(Whh, wimg);
  k_prep_ge<<<dim3(9, 8), 256, 0, stream>>>(emb, Wih, bih, ge);

  hipFuncSetAttribute(reinterpret_cast<const void*>(k_gru),
                      hipFuncAttributeMaxDynamicSharedMemorySize, LDS_BYTES);
  k_gru<<<NG * NW, 64, LDS_BYTES, stream>>>(x, ge, bhh, wimg, h16, h32, cnt);

  k_fc<<<dim3(3, 8), 256, 0, stream>>>(h32, fcW, fcb, out);
}

// Round 7
// 2313.931 us; speedup vs baseline: 1.4386x; 1.4386x over previous
//
#include <hip/hip_runtime.h>

#define DI __device__ __forceinline__

constexpr int BB   = 128;   // batch
constexpr int TT   = 512;   // seq len
constexpr int HH   = 768;   // hidden
constexpr int G3   = 3 * HH;   // 2304
constexpr int VOC  = 128;

// partitioning: 8 row-groups (16 rows) x 48 unit-waves (16 units), 1 wave per block
constexpr int NG   = 8;     // sync groups (16 batch rows each)
constexpr int NW   = 48;    // waves per group (16 units each)
constexpr int KC   = 24;    // k-chunks of 32 (768 = 24*32)
constexpr int FPAD = 16;    // flag padding (ints) -> 64B per flag

// workspace offsets (bytes); total ~5.53 MB
constexpr size_t OFF_GE   = 0;                      // [VOC][G3] f32  = 1,179,648
constexpr size_t OFF_WIMG = 1179648;                // [NW][3][KC][64][8] f16 = 3,538,944
constexpr size_t OFF_H16  = OFF_WIMG + 3538944;     // [2][BB][HH] f16 = 393,216
constexpr size_t OFF_H32  = OFF_H16 + 393216;       // [BB][HH] f32   = 393,216
constexpr size_t OFF_FLG  = OFF_H32 + 393216;       // [NG][NW][16] int = 24,576

constexpr int LDS_W_BYTES = 3 * KC * 64 * 16;       // 73,728 (W fragments)
constexpr int LDS_BYTES   = LDS_W_BYTES + 1024;     // 74,752 -> 2 blocks/CU

typedef _Float16 f16x8 __attribute__((ext_vector_type(8)));
typedef float    f32x4 __attribute__((ext_vector_type(4)));

DI float sigm(float x) { return __builtin_amdgcn_rcpf(1.0f + __expf(-x)); }
DI float tanh_fast(float x) {
  float e = __expf(-2.0f * fabsf(x));
  float r = (1.0f - e) * __builtin_amdgcn_rcpf(1.0f + e);
  return copysignf(r, x);
}

// device-scope (sc1 only): bypass L1/L2, serviced at MALL -- coherent across XCDs
DI f16x8 load_dc_x4(const void* p) {
  f16x8 r;
  asm volatile("global_load_dwordx4 %0, %1, off sc1"
               : "=v"(r) : "v"(p) : "memory");
  return r;
}
DI void store_dc_x2(void* p, uint2 v) {
  asm volatile("global_store_dwordx2 %0, %1, off sc1"
               :: "v"(p), "v"(v) : "memory");
}
DI int load_flag(const int* p) {
  int r;
  asm volatile("global_load_dword %0, %1, off sc1\n\ts_waitcnt vmcnt(0)"
               : "=v"(r) : "v"(p) : "memory");
  return r;
}
DI void store_flag(int* p, int v) {
  asm volatile("global_store_dword %0, %1, off sc1"
               :: "v"(p), "v"(v) : "memory");
}
DI void wait_vm0() { asm volatile("s_waitcnt vmcnt(0)" ::: "memory"); }
DI void wait_lgkm0() { asm volatile("s_waitcnt lgkmcnt(0)" ::: "memory"); }

// ---------------- K0: zero flags ----------------
__global__ void k_zero(int* flg, int n) {
  int i = blockIdx.x * 256 + threadIdx.x;
  if (i < n) flg[i] = 0;
}

// ---------------- K1: W_hh -> fp16 MFMA B-fragment image ----------------
// layout [tile 48][gate 3][kc 24][lane 64] f16x8
// B[k][n]: n = tile*16 + (lane&15), k = kc*32 + (lane>>4)*8 + q
// value = W_hh[gate*768 + n][k]
__global__ void k_prep_w(const float* __restrict__ Whh, _Float16* __restrict__ wimg) {
  int tid = blockIdx.x * 256 + threadIdx.x;       // 48*3*24*64 = 221,184 total
  if (tid >= NW * 3 * KC * 64) return;
  int l  = tid & 63;
  int fi = tid >> 6;
  int kc = fi % KC;
  int nt = (fi / KC) % 3;
  int j  = fi / (KC * 3);
  int g  = nt * HH + j * 16 + (l & 15);
  int k0 = kc * 32 + (l >> 4) * 8;
  const float* src = Whh + (size_t)g * HH + k0;
  f16x8 o;
#pragma unroll
  for (int q = 0; q < 8; ++q) o[q] = (_Float16)src[q];
  ((f16x8*)wimg)[tid] = o;
}

// ---------------- K2: ge[v][g] = emb[v,:] . W_ih[g,:] + b_ih[g] ----------------
__global__ void k_prep_ge(const float* __restrict__ emb, const float* __restrict__ Wih,
                          const float* __restrict__ bih, float* __restrict__ ge) {
  int g  = blockIdx.x * 256 + threadIdx.x;
  int v0 = blockIdx.y * 16;
  float acc[16];
  float b = bih[g];
#pragma unroll
  for (int i = 0; i < 16; ++i) acc[i] = b;
  const float* wrow = Wih + (size_t)g * HH;
  for (int e = 0; e < HH; e += 4) {
    float4 w = *(const float4*)(wrow + e);
#pragma unroll
    for (int i = 0; i < 16; ++i) {
      float4 m = *(const float4*)(emb + (size_t)(v0 + i) * HH + e);
      acc[i] = fmaf(w.x, m.x, acc[i]);
      acc[i] = fmaf(w.y, m.y, acc[i]);
      acc[i] = fmaf(w.z, m.z, acc[i]);
      acc[i] = fmaf(w.w, m.w, acc[i]);
    }
  }
#pragma unroll
  for (int i = 0; i < 16; ++i) ge[(size_t)(v0 + i) * G3 + g] = acc[i];
}

// ---------------- K3: persistent GRU recurrence ----------------
// 384 blocks x 64 thr (1 wave). block -> (grp = bid/NW, j = bid%NW):
// rows [16*grp,+16) x units [16*j,+16). flag[grp][j] = t+1 <=> tile published for step t+1.
__global__ __launch_bounds__(64, 1) void k_gru(
    const int* __restrict__ x,       // [BB][TT]
    const float* __restrict__ ge,    // [VOC][G3]
    const float* __restrict__ bhh,   // [G3]
    const _Float16* __restrict__ wimg,
    _Float16* h16,                   // [2][BB][HH]
    float* __restrict__ h32,         // [BB][HH]
    int* flg)                        // [NG][NW][FPAD]
{
  extern __shared__ char smem[];
  _Float16* st = (_Float16*)(smem + LDS_W_BYTES);   // [16][20] halfs

  const int lane = threadIdx.x;
  const int bid  = blockIdx.x;
  const int grp  = bid / NW;
  const int j    = bid % NW;
  const int bm   = grp * 16;        // this wave's 16 batch rows
  const int u0   = j * 16;          // this wave's 16 hidden units
  int* gflg = flg + grp * NW * FPAD;

  // stage this tile's W fragments into LDS (73,728 B = 4608 uint4 / 64 = 72)
  {
    const uint4* src = (const uint4*)(wimg + (size_t)j * (3 * KC * 64 * 8));
    uint4* dst = (uint4*)smem;
#pragma unroll 8
    for (int r = 0; r < 72; ++r) dst[lane + 64 * r] = src[lane + 64 * r];
  }

  const int c16 = lane & 15;   // D col / A row within tile
  const int kr  = lane >> 4;   // k sub-chunk selector

  const float bh_r = bhh[0 * HH + u0 + c16];
  const float bh_z = bhh[1 * HH + u0 + c16];
  const float bh_n = bhh[2 * HH + u0 + c16];

  float hprev[4] = {0.f, 0.f, 0.f, 0.f};

  _Float16* hb0 = h16;
  _Float16* hb1 = h16 + (size_t)BB * HH;
  const f16x8* bfr = (const f16x8*)smem;

  // poll address for this wave: lanes 0..47 watch the 48 producers (48..63 duplicate)
  const int fidx = (lane < NW) ? lane : (lane - NW);
  const int* fpoll = gflg + fidx * FPAD;

  // prologue gathers for t=0
  float ger[4], gez[4], gen[4];
#pragma unroll
  for (int q = 0; q < 4; ++q) {
    int xv = x[(size_t)(bm + kr * 4 + q) * TT + 0];
    const float* gp = ge + (size_t)xv * G3 + u0 + c16;
    ger[q] = gp[0 * HH];
    gez[q] = gp[1 * HH];
    gen[q] = gp[2 * HH];
  }

  int budget = 1 << 20;   // global poll budget: bug => wrong result, not timeout

  for (int t = 0; t < TT; ++t) {
    // prefetch next-step token ids early (cached; consumed in the tail)
    int xvn[4];
    if (t < TT - 1) {
#pragma unroll
      for (int q = 0; q < 4; ++q)
        xvn[q] = x[(size_t)(bm + kr * 4 + q) * TT + (t + 1)];
    }

    f32x4 acc0 = {bh_r, bh_r, bh_r, bh_r};
    f32x4 acc1 = {bh_z, bh_z, bh_z, bh_z};
    f32x4 acc2 = {bh_n, bh_n, bh_n, bh_n};

    if (t > 0) {
      // ---- poll all 48 producer flags of this group (parallel lane loads) ----
      for (;;) {
        int f = load_flag(fpoll);
        if (__all(f >= t)) break;
        if (--budget < 0) break;
      }
      asm volatile("" ::: "memory");  // keep A-loads below the poll

      // ---- A fragments: 24 x 16B device-scope loads (MALL hits) ----
      const _Float16* hb = (t & 1) ? hb1 : hb0;
      const char* ab = (const char*)(hb + (size_t)(bm + c16) * HH) + kr * 16;
      f16x8 a[KC];
#pragma unroll
      for (int kc = 0; kc < KC; ++kc) a[kc] = load_dc_x4(ab + kc * 64);
      wait_vm0();
      __builtin_amdgcn_sched_barrier(0);  // MFMAs must not hoist above the wait

      // ---- gh = h . W^T : 3 gates x 24 k-chunks, B from LDS ----
#pragma unroll
      for (int kc = 0; kc < KC; ++kc) {
        acc0 = __builtin_amdgcn_mfma_f32_16x16x32_f16(a[kc], bfr[(0 * KC + kc) * 64 + lane], acc0, 0, 0, 0);
        acc1 = __builtin_amdgcn_mfma_f32_16x16x32_f16(a[kc], bfr[(1 * KC + kc) * 64 + lane], acc1, 0, 0, 0);
        acc2 = __builtin_amdgcn_mfma_f32_16x16x32_f16(a[kc], bfr[(2 * KC + kc) * 64 + lane], acc2, 0, 0, 0);
      }
    }

    // ---- gates + state update (fp32) ----
    float hv[4];
#pragma unroll
    for (int q = 0; q < 4; ++q) {
      float r = sigm(acc0[q] + ger[q]);
      float z = sigm(acc1[q] + gez[q]);
      float n = tanh_fast(gen[q] + r * acc2[q]);
      float h = n + z * (hprev[q] - n);
      hprev[q] = h;
      hv[q] = h;
    }

    if (t == TT - 1) {
#pragma unroll
      for (int q = 0; q < 4; ++q)
        h32[(size_t)(bm + kr * 4 + q) * HH + u0 + c16] = hv[q];
    } else {
      // ---- pack 16x16 f16 tile via LDS (stride 20) ----
#pragma unroll
      for (int q = 0; q < 4; ++q)
        st[(kr * 4 + q) * 20 + c16] = (_Float16)hv[q];

      // ---- issue t+1 ge gathers now (cached loads, xvn already resident) ----
#pragma unroll
      for (int q = 0; q < 4; ++q) {
        const float* gp = ge + (size_t)xvn[q] * G3 + u0 + c16;
        ger[q] = gp[0 * HH];
        gez[q] = gp[1 * HH];
        gen[q] = gp[2 * HH];
      }

      wait_lgkm0();
      __builtin_amdgcn_sched_barrier(0);
      int rr = lane >> 2;       // row within tile
      int qq = lane & 3;        // 4-unit quarter
      uint2 v = *(const uint2*)&st[rr * 20 + qq * 4];
      _Float16* hn = (t & 1) ? hb0 : hb1;   // buf[(t+1)&1]
      store_dc_x2((char*)(hn + (size_t)(bm + rr) * HH + u0 + qq * 4), v);

      wait_vm0();               // h stores (and gathers) done before flag
      if (lane == 0) store_flag(gflg + j * FPAD, t + 1);
    }
  }
}

// ---------------- K4: out = h32 @ fc_W^T + fc_b ----------------
__global__ void k_fc(const float* __restrict__ h32, const float* __restrict__ fcW,
                     const float* __restrict__ fcb, float* __restrict__ out) {
  int o  = blockIdx.x * 256 + threadIdx.x;   // 768
  int b0 = blockIdx.y * 16;                  // 128
  float acc[16];
  float bi = fcb[o];
#pragma unroll
  for (int i = 0; i < 16; ++i) acc[i] = bi;
  const float* wrow = fcW + (size_t)o * HH;
  for (int e = 0; e < HH; e += 4) {
    float4 w = *(const float4*)(wrow + e);
#pragma unroll
    for (int i = 0; i < 16; ++i) {
      float4 m = *(const float4*)(h32 + (size_t)(b0 + i) * HH + e);
      acc[i] = fmaf(w.x, m.x, acc[i]);
      acc[i] = fmaf(w.y, m.y, acc[i]);
      acc[i] = fmaf(w.z, m.z, acc[i]);
      acc[i] = fmaf(w.w, m.w, acc[i]);
    }
  }
#pragma unroll
  for (int i = 0; i < 16; ++i) out[(size_t)(b0 + i) * HH + o] = acc[i];
}

extern "C" void kernel_launch(void* const* d_in, const int* in_sizes, int n_in,
                              void* d_out, int out_size, void* d_ws, size_t ws_size,
                              hipStream_t stream) {
  const int*   x   = (const int*)d_in[0];
  const float* emb = (const float*)d_in[1];
  const float* Wih = (const float*)d_in[2];
  const float* Whh = (const float*)d_in[3];
  const float* bih = (const float*)d_in[4];
  const float* bhh = (const float*)d_in[5];
  const float* fcW = (const float*)d_in[6];
  const float* fcb = (const float*)d_in[7];
  float* out = (float*)d_out;

  char* ws = (char*)d_ws;
  float*     ge   = (float*)(ws + OFF_GE);
  _Float16*  wimg = (_Float16*)(ws + OFF_WIMG);
  _Float16*  h16  = (_Float16*)(ws + OFF_H16);
  float*     h32  = (float*)(ws + OFF_H32);
  int*       flg  = (int*)(ws + OFF_FLG);

  // zero padded flags (8 * 48 * 16 = 6144 ints)
  k_zero<<<24, 256, 0, stream>>>(flg, NG * NW * FPAD);
  k_prep_w<<<864, 256, 0, stream>>>(Whh, wimg);
  k_prep_ge<<<dim3(9, 8), 256, 0, stream>>>(emb, Wih, bih, ge);

  hipFuncSetAttribute(reinterpret_cast<const void*>(k_gru),
                      hipFuncAttributeMaxDynamicSharedMemorySize, LDS_BYTES);
  k_gru<<<NG * NW, 64, LDS_BYTES, stream>>>(x, ge, bhh, wimg, h16, h32, flg);

  k_fc<<<dim3(3, 8), 256, 0, stream>>>(h32, fcW, fcb, out);
}